// Round 1
// baseline (2850.059 us; speedup 1.0000x reference)
//
#include <hip/hip_runtime.h>

#define U_CNT 300000
#define I_CNT 200000
#define N_CNT (U_CNT + I_CNT)
#define DIM 64

// ---------------- kernels ----------------

__global__ void deg_kernel(const int* __restrict__ col, float* __restrict__ deg, int E) {
    int e = blockIdx.x * blockDim.x + threadIdx.x;
    if (e < E) unsafeAtomicAdd(&deg[col[e]], 1.0f);
}

__global__ void dis_kernel(const float* __restrict__ deg, float* __restrict__ dis, int n) {
    int i = blockIdx.x * blockDim.x + threadIdx.x;
    if (i < n) {
        float d = deg[i];
        dis[i] = d > 0.0f ? rsqrtf(d) : 0.0f;
    }
}

__global__ void copy4_kernel(const float4* __restrict__ src, float4* __restrict__ dst, int n) {
    int i = blockIdx.x * blockDim.x + threadIdx.x;
    if (i < n) dst[i] = src[i];
}

__global__ void add4_kernel(float4* __restrict__ dst, const float4* __restrict__ src, int n) {
    int i = blockIdx.x * blockDim.x + threadIdx.x;
    if (i < n) {
        float4 a = dst[i], b = src[i];
        a.x += b.x; a.y += b.y; a.z += b.z; a.w += b.w;
        dst[i] = a;
    }
}

__global__ void scale4_kernel(float4* __restrict__ p, int n, float s) {
    int i = blockIdx.x * blockDim.x + threadIdx.x;
    if (i < n) {
        float4 a = p[i];
        a.x *= s; a.y *= s; a.z *= s; a.w *= s;
        p[i] = a;
    }
}

// One 64-lane wave per edge; lane index = feature dim.
// e is wave-uniform (threadIdx.x>>6 is constant across the wave) so row/col/dis
// loads become scalar; x[row] gather is a coalesced 256B read.
__global__ void prop_kernel(const int* __restrict__ row, const int* __restrict__ col,
                            const float* __restrict__ dis,
                            const float* __restrict__ srcU, const float* __restrict__ srcI,
                            float* __restrict__ dstU, float* __restrict__ dstI, int E) {
    int e = blockIdx.x * 4 + (threadIdx.x >> 6);
    if (e >= E) return;
    int d = threadIdx.x & 63;
    int r = row[e], c = col[e];
    float nrm = dis[r] * dis[c];
    const float* s = (r < U_CNT) ? srcU + (size_t)r * DIM : srcI + (size_t)(r - U_CNT) * DIM;
    float*       t = (c < U_CNT) ? dstU + (size_t)c * DIM : dstI + (size_t)(c - U_CNT) * DIM;
    unsafeAtomicAdd(&t[d], nrm * s[d]);
}

// ---------------- host ----------------

extern "C" void kernel_launch(void* const* d_in, const int* in_sizes, int n_in,
                              void* d_out, int out_size, void* d_ws, size_t ws_size,
                              hipStream_t stream) {
    const int*   edge = (const int*)d_in[0];
    const float* embU = (const float*)d_in[1];
    const float* embI = (const float*)d_in[2];
    const int E = in_sizes[0] / 2;
    const int* row = edge;
    const int* col = edge + E;

    float* out  = (float*)d_out;
    float* accU = out;                                   // users_final (accumulator)
    float* cu   = out + (size_t)U_CNT * DIM;             // users copy (scratch until end)
    float* accI = out + (size_t)2 * U_CNT * DIM;         // items_final (accumulator)
    float* ci   = accI + (size_t)I_CNT * DIM;            // items copy (scratch until end)

    float* bufA   = (float*)d_ws;                        // N*DIM floats (128 MB)
    float* bufA_U = bufA;
    float* bufA_I = bufA + (size_t)U_CNT * DIM;
    float* deg    = bufA + (size_t)N_CNT * DIM;          // N floats
    float* dis    = deg + N_CNT;                         // N floats

    const int B = 256;
    const int nU4 = U_CNT * DIM / 4;
    const int nI4 = I_CNT * DIM / 4;
    const int gU4 = (nU4 + B - 1) / B;
    const int gI4 = (nI4 + B - 1) / B;
    const int gProp = (E + 3) / 4;

    // degrees + normalization
    hipMemsetAsync(deg, 0, (size_t)N_CNT * sizeof(float), stream);
    deg_kernel<<<(E + B - 1) / B, B, 0, stream>>>(col, deg, E);
    dis_kernel<<<(N_CNT + B - 1) / B, B, 0, stream>>>(deg, dis, N_CNT);

    // acc = x0
    copy4_kernel<<<gU4, B, 0, stream>>>((const float4*)embU, (float4*)accU, nU4);
    copy4_kernel<<<gI4, B, 0, stream>>>((const float4*)embI, (float4*)accI, nI4);

    // layer 1: inputs -> bufA
    hipMemsetAsync(bufA, 0, (size_t)N_CNT * DIM * sizeof(float), stream);
    prop_kernel<<<gProp, B, 0, stream>>>(row, col, dis, embU, embI, bufA_U, bufA_I, E);
    add4_kernel<<<gU4, B, 0, stream>>>((float4*)accU, (const float4*)bufA_U, nU4);
    add4_kernel<<<gI4, B, 0, stream>>>((float4*)accI, (const float4*)bufA_I, nI4);

    // layer 2: bufA -> (cu, ci)
    hipMemsetAsync(cu, 0, (size_t)U_CNT * DIM * sizeof(float), stream);
    hipMemsetAsync(ci, 0, (size_t)I_CNT * DIM * sizeof(float), stream);
    prop_kernel<<<gProp, B, 0, stream>>>(row, col, dis, bufA_U, bufA_I, cu, ci, E);
    add4_kernel<<<gU4, B, 0, stream>>>((float4*)accU, (const float4*)cu, nU4);
    add4_kernel<<<gI4, B, 0, stream>>>((float4*)accI, (const float4*)ci, nI4);

    // layer 3: (cu, ci) -> bufA
    hipMemsetAsync(bufA, 0, (size_t)N_CNT * DIM * sizeof(float), stream);
    prop_kernel<<<gProp, B, 0, stream>>>(row, col, dis, cu, ci, bufA_U, bufA_I, E);
    add4_kernel<<<gU4, B, 0, stream>>>((float4*)accU, (const float4*)bufA_U, nU4);
    add4_kernel<<<gI4, B, 0, stream>>>((float4*)accI, (const float4*)bufA_I, nI4);

    // layer 4: bufA -> (cu, ci)
    hipMemsetAsync(cu, 0, (size_t)U_CNT * DIM * sizeof(float), stream);
    hipMemsetAsync(ci, 0, (size_t)I_CNT * DIM * sizeof(float), stream);
    prop_kernel<<<gProp, B, 0, stream>>>(row, col, dis, bufA_U, bufA_I, cu, ci, E);
    add4_kernel<<<gU4, B, 0, stream>>>((float4*)accU, (const float4*)cu, nU4);
    add4_kernel<<<gI4, B, 0, stream>>>((float4*)accI, (const float4*)ci, nI4);

    // finalize: acc /= 25, then overwrite scratch regions with the input copies
    const float s = 1.0f / 25.0f;
    scale4_kernel<<<gU4, B, 0, stream>>>((float4*)accU, nU4, s);
    scale4_kernel<<<gI4, B, 0, stream>>>((float4*)accI, nI4, s);
    copy4_kernel<<<gU4, B, 0, stream>>>((const float4*)embU, (float4*)cu, nU4);
    copy4_kernel<<<gI4, B, 0, stream>>>((const float4*)embI, (float4*)ci, nI4);
}

// Round 2
// 1503.672 us; speedup vs baseline: 1.8954x; 1.8954x over previous
//
#include <hip/hip_runtime.h>

#define U_CNT 300000
#define I_CNT 200000
#define N_CNT (U_CNT + I_CNT)
#define DIM 64
#define SCAN_CHUNK 1024           // elems per scan block (256 thr x 4)
#define NB1 ((N_CNT + SCAN_CHUNK - 1) / SCAN_CHUNK)   // 489 blocks

// ---------------- degree / normalization ----------------

__global__ void deg_cnt_kernel(const int* __restrict__ col, int* __restrict__ cnt, int E) {
    int e = blockIdx.x * blockDim.x + threadIdx.x;
    if (e < E) atomicAdd(&cnt[col[e]], 1);
}

__global__ void dis_kernel(const int* __restrict__ cnt, float* __restrict__ dis, int n) {
    int i = blockIdx.x * blockDim.x + threadIdx.x;
    if (i < n) {
        int d = cnt[i];
        dis[i] = d > 0 ? rsqrtf((float)d) : 0.0f;
    }
}

// ---------------- prefix sum (3-kernel scan) ----------------

__global__ void scan1_kernel(const int* __restrict__ cnt, int* __restrict__ bsum, int n) {
    __shared__ int lds[256];
    int t = threadIdx.x;
    int i = blockIdx.x * SCAN_CHUNK + t * 4;
    int4 v = make_int4(0, 0, 0, 0);
    if (i + 3 < n) v = *(const int4*)(cnt + i);
    else {
        if (i     < n) v.x = cnt[i];
        if (i + 1 < n) v.y = cnt[i + 1];
        if (i + 2 < n) v.z = cnt[i + 2];
        if (i + 3 < n) v.w = cnt[i + 3];
    }
    lds[t] = v.x + v.y + v.z + v.w;
    __syncthreads();
    for (int o = 128; o > 0; o >>= 1) {
        if (t < o) lds[t] += lds[t + o];
        __syncthreads();
    }
    if (t == 0) bsum[blockIdx.x] = lds[0];
}

__global__ void scan2_kernel(int* __restrict__ bsum, int nb) {
    __shared__ int lds[512];
    int t = threadIdx.x;
    int v = (t < nb) ? bsum[t] : 0;
    lds[t] = v;
    __syncthreads();
    for (int o = 1; o < 512; o <<= 1) {
        int a = lds[t] + ((t >= o) ? lds[t - o] : 0);
        __syncthreads();
        lds[t] = a;
        __syncthreads();
    }
    if (t < nb) bsum[t] = lds[t] - v;   // exclusive
}

__global__ void scan3_kernel(const int* __restrict__ cnt, const int* __restrict__ bsum,
                             int* __restrict__ off, int* __restrict__ cur, int n, int E) {
    __shared__ int lds[256];
    int t = threadIdx.x;
    int i = blockIdx.x * SCAN_CHUNK + t * 4;
    int4 v = make_int4(0, 0, 0, 0);
    if (i + 3 < n) v = *(const int4*)(cnt + i);
    else {
        if (i     < n) v.x = cnt[i];
        if (i + 1 < n) v.y = cnt[i + 1];
        if (i + 2 < n) v.z = cnt[i + 2];
        if (i + 3 < n) v.w = cnt[i + 3];
    }
    int s = v.x + v.y + v.z + v.w;
    lds[t] = s;
    __syncthreads();
    for (int o = 1; o < 256; o <<= 1) {
        int a = lds[t] + ((t >= o) ? lds[t - o] : 0);
        __syncthreads();
        lds[t] = a;
        __syncthreads();
    }
    int ex = lds[t] - s + bsum[blockIdx.x];
    int o0 = ex, o1 = ex + v.x, o2 = o1 + v.y, o3 = o2 + v.z;
    if (i     < n) { off[i]     = o0; cur[i]     = o0; }
    if (i + 1 < n) { off[i + 1] = o1; cur[i + 1] = o1; }
    if (i + 2 < n) { off[i + 2] = o2; cur[i + 2] = o2; }
    if (i + 3 < n) { off[i + 3] = o3; cur[i + 3] = o3; }
    if (i == n - 4 || (i <= n && i + 4 > n)) off[n] = E;  // sentinel
}

__global__ void fill_kernel(const int* __restrict__ row, const int* __restrict__ col,
                            const float* __restrict__ dis, int* __restrict__ cur,
                            int2* __restrict__ csr, int E) {
    int e = blockIdx.x * blockDim.x + threadIdx.x;
    if (e < E) {
        int r = row[e], c = col[e];
        int p = atomicAdd(&cur[c], 1);
        int2 pr;
        pr.x = r;
        pr.y = __float_as_int(dis[r] * dis[c]);
        csr[p] = pr;
    }
}

// ---------------- gather propagation (fused acc update) ----------------
// one 64-lane wave per destination node; lane = feature dim
__global__ __launch_bounds__(256) void gather_kernel(
        const int* __restrict__ off, const int2* __restrict__ csr,
        const float* __restrict__ srcU, const float* __restrict__ srcIadj,
        float* __restrict__ yU, float* __restrict__ yIadj,
        float* __restrict__ accU, float* __restrict__ accIadj,
        int writeY, float accScale) {
    int n = blockIdx.x * 4 + (threadIdx.x >> 6);
    if (n >= N_CNT) return;
    int lane = threadIdx.x & 63;
    int s = off[n], e = off[n + 1];
    float a = 0.0f;
    int i = s;
    for (; i + 2 <= e; i += 2) {
        int2 p0 = csr[i], p1 = csr[i + 1];
        const float* x0 = (p0.x < U_CNT ? srcU : srcIadj) + (size_t)p0.x * DIM;
        const float* x1 = (p1.x < U_CNT ? srcU : srcIadj) + (size_t)p1.x * DIM;
        float v0 = x0[lane], v1 = x1[lane];
        a = fmaf(__int_as_float(p0.y), v0, a);
        a = fmaf(__int_as_float(p1.y), v1, a);
    }
    if (i < e) {
        int2 p0 = csr[i];
        const float* x0 = (p0.x < U_CNT ? srcU : srcIadj) + (size_t)p0.x * DIM;
        a = fmaf(__int_as_float(p0.y), x0[lane], a);
    }
    size_t base = (size_t)n * DIM + lane;
    float* ap = (n < U_CNT ? accU : accIadj) + base;
    if (writeY) {
        float* yp = (n < U_CNT ? yU : yIadj) + base;
        yp[lane * 0] = a;   // lane already in base
    }
    *ap = (*ap + a) * accScale;
}

// ---------------- utility ----------------

__global__ void copy4_kernel(const float4* __restrict__ src, float4* __restrict__ dst, int n) {
    int i = blockIdx.x * blockDim.x + threadIdx.x;
    if (i < n) dst[i] = src[i];
}

// ---------------- host ----------------

extern "C" void kernel_launch(void* const* d_in, const int* in_sizes, int n_in,
                              void* d_out, int out_size, void* d_ws, size_t ws_size,
                              hipStream_t stream) {
    const int*   edge = (const int*)d_in[0];
    const float* embU = (const float*)d_in[1];
    const float* embI = (const float*)d_in[2];
    const int E = in_sizes[0] / 2;
    const int* row = edge;
    const int* col = edge + E;

    float* out  = (float*)d_out;
    float* accU = out;
    float* cu   = out + (size_t)U_CNT * DIM;
    float* accI = out + (size_t)2 * U_CNT * DIM;
    float* ci   = accI + (size_t)I_CNT * DIM;

    // workspace carve-up (16B aligned chunks)
    char* ws = (char*)d_ws;
    size_t p = 0;
    float* bufA = (float*)(ws + p); p += (size_t)N_CNT * DIM * sizeof(float);   // 128 MB
    int*   cnt  = (int*)(ws + p);   p += ((size_t)N_CNT + 4) * sizeof(int);
    int*   off  = (int*)(ws + p);   p += ((size_t)N_CNT + 4) * sizeof(int);
    int*   cur  = (int*)(ws + p);   p += ((size_t)N_CNT + 4) * sizeof(int);
    float* dis  = (float*)(ws + p); p += ((size_t)N_CNT + 4) * sizeof(float);
    int*   bsum = (int*)(ws + p);   p += 1024 * sizeof(int);
    int2*  csr  = (int2*)(ws + p);  p += (size_t)E * sizeof(int2);              // 20 MB

    float* bufA_U = bufA;
    float* bufA_I = bufA + (size_t)U_CNT * DIM;

    // "adjusted" item pointers so kernels index with global node id directly
    const float* embIadj  = embI - (size_t)U_CNT * DIM;
    float* bufA_Iadj = bufA_I - (size_t)U_CNT * DIM;
    float* ciadj     = ci   - (size_t)U_CNT * DIM;
    float* accIadj   = accI - (size_t)U_CNT * DIM;

    const int B = 256;
    const int nU4 = U_CNT * DIM / 4;
    const int nI4 = I_CNT * DIM / 4;
    const int gU4 = (nU4 + B - 1) / B;
    const int gI4 = (nI4 + B - 1) / B;
    const int gE  = (E + B - 1) / B;
    const int gN  = (N_CNT + B - 1) / B;
    const int gGather = (N_CNT + 3) / 4;

    // 1. degree + normalization
    hipMemsetAsync(cnt, 0, (size_t)N_CNT * sizeof(int), stream);
    deg_cnt_kernel<<<gE, B, 0, stream>>>(col, cnt, E);
    dis_kernel<<<gN, B, 0, stream>>>(cnt, dis, N_CNT);

    // 2. CSR build
    scan1_kernel<<<NB1, 256, 0, stream>>>(cnt, bsum, N_CNT);
    scan2_kernel<<<1, 512, 0, stream>>>(bsum, NB1);
    scan3_kernel<<<NB1, 256, 0, stream>>>(cnt, bsum, off, cur, N_CNT, E);
    fill_kernel<<<gE, B, 0, stream>>>(row, col, dis, cur, csr, E);

    // 3. acc = x0
    copy4_kernel<<<gU4, B, 0, stream>>>((const float4*)embU, (float4*)accU, nU4);
    copy4_kernel<<<gI4, B, 0, stream>>>((const float4*)embI, (float4*)accI, nI4);

    // 4. four propagation layers (acc += y fused; L4 writes no y and scales)
    gather_kernel<<<gGather, B, 0, stream>>>(off, csr, embU, embIadj,
                                             bufA_U, bufA_Iadj, accU, accIadj, 1, 1.0f);
    gather_kernel<<<gGather, B, 0, stream>>>(off, csr, bufA_U, bufA_Iadj,
                                             cu, ciadj, accU, accIadj, 1, 1.0f);
    gather_kernel<<<gGather, B, 0, stream>>>(off, csr, cu, ciadj,
                                             bufA_U, bufA_Iadj, accU, accIadj, 1, 1.0f);
    gather_kernel<<<gGather, B, 0, stream>>>(off, csr, bufA_U, bufA_Iadj,
                                             nullptr, nullptr, accU, accIadj, 0, 1.0f / 25.0f);

    // 5. overwrite scratch output regions with the verbatim input copies
    copy4_kernel<<<gU4, B, 0, stream>>>((const float4*)embU, (float4*)cu, nU4);
    copy4_kernel<<<gI4, B, 0, stream>>>((const float4*)embI, (float4*)ci, nI4);
}

// Round 3
// 821.098 us; speedup vs baseline: 3.4710x; 1.8313x over previous
//
#include <hip/hip_runtime.h>

#define U_CNT 300000
#define I_CNT 200000
#define N_CNT (U_CNT + I_CNT)
#define DIM 64
#define SCAN_CHUNK 1024
#define NB1 ((N_CNT + SCAN_CHUNK - 1) / SCAN_CHUNK)   // 489

typedef unsigned short bf16_t;

__device__ __forceinline__ float b2f(bf16_t u) {
    return __uint_as_float(((unsigned)u) << 16);
}
__device__ __forceinline__ bf16_t f2b(float f) {
    unsigned u = __float_as_uint(f);
    u += 0x7FFFu + ((u >> 16) & 1u);     // round-to-nearest-even
    return (bf16_t)(u >> 16);
}

// ---------------- degree / normalization ----------------

__global__ void deg_cnt_kernel(const int* __restrict__ col, int* __restrict__ cnt, int E) {
    int e = blockIdx.x * blockDim.x + threadIdx.x;
    if (e < E) atomicAdd(&cnt[col[e]], 1);
}

__global__ void dis_kernel(const int* __restrict__ cnt, float* __restrict__ dis, int n) {
    int i = blockIdx.x * blockDim.x + threadIdx.x;
    if (i < n) {
        int d = cnt[i];
        dis[i] = d > 0 ? rsqrtf((float)d) : 0.0f;
    }
}

// ---------------- prefix sum ----------------

__global__ void scan1_kernel(const int* __restrict__ cnt, int* __restrict__ bsum, int n) {
    __shared__ int lds[256];
    int t = threadIdx.x;
    int i = blockIdx.x * SCAN_CHUNK + t * 4;
    int4 v = make_int4(0, 0, 0, 0);
    if (i + 3 < n) v = *(const int4*)(cnt + i);
    else {
        if (i     < n) v.x = cnt[i];
        if (i + 1 < n) v.y = cnt[i + 1];
        if (i + 2 < n) v.z = cnt[i + 2];
        if (i + 3 < n) v.w = cnt[i + 3];
    }
    lds[t] = v.x + v.y + v.z + v.w;
    __syncthreads();
    for (int o = 128; o > 0; o >>= 1) {
        if (t < o) lds[t] += lds[t + o];
        __syncthreads();
    }
    if (t == 0) bsum[blockIdx.x] = lds[0];
}

__global__ void scan2_kernel(int* __restrict__ bsum, int nb) {
    __shared__ int lds[512];
    int t = threadIdx.x;
    int v = (t < nb) ? bsum[t] : 0;
    lds[t] = v;
    __syncthreads();
    for (int o = 1; o < 512; o <<= 1) {
        int a = lds[t] + ((t >= o) ? lds[t - o] : 0);
        __syncthreads();
        lds[t] = a;
        __syncthreads();
    }
    if (t < nb) bsum[t] = lds[t] - v;
}

__global__ void scan3_kernel(const int* __restrict__ cnt, const int* __restrict__ bsum,
                             int* __restrict__ off, int* __restrict__ cur, int n, int E) {
    __shared__ int lds[256];
    int t = threadIdx.x;
    int i = blockIdx.x * SCAN_CHUNK + t * 4;
    int4 v = make_int4(0, 0, 0, 0);
    if (i + 3 < n) v = *(const int4*)(cnt + i);
    else {
        if (i     < n) v.x = cnt[i];
        if (i + 1 < n) v.y = cnt[i + 1];
        if (i + 2 < n) v.z = cnt[i + 2];
        if (i + 3 < n) v.w = cnt[i + 3];
    }
    int s = v.x + v.y + v.z + v.w;
    lds[t] = s;
    __syncthreads();
    for (int o = 1; o < 256; o <<= 1) {
        int a = lds[t] + ((t >= o) ? lds[t - o] : 0);
        __syncthreads();
        lds[t] = a;
        __syncthreads();
    }
    int ex = lds[t] - s + bsum[blockIdx.x];
    int o0 = ex, o1 = ex + v.x, o2 = o1 + v.y, o3 = o2 + v.z;
    if (i     < n) { off[i]     = o0; cur[i]     = o0; }
    if (i + 1 < n) { off[i + 1] = o1; cur[i + 1] = o1; }
    if (i + 2 < n) { off[i + 2] = o2; cur[i + 2] = o2; }
    if (i + 3 < n) { off[i + 3] = o3; cur[i + 3] = o3; }
    if (i == n - 4) off[n] = E;   // n % 4 == 0 here (N_CNT = 500000)
}

__global__ void fill_kernel(const int* __restrict__ row, const int* __restrict__ col,
                            const float* __restrict__ dis, int* __restrict__ cur,
                            int2* __restrict__ csr, int E) {
    int e = blockIdx.x * blockDim.x + threadIdx.x;
    if (e < E) {
        int r = row[e], c = col[e];
        int p = atomicAdd(&cur[c], 1);
        int2 pr;
        pr.x = r;
        pr.y = __float_as_int(dis[r] * dis[c]);
        csr[p] = pr;
    }
}

// ---------------- f32 -> bf16 conversion ----------------

__global__ void f2b_kernel(const float4* __restrict__ src, ushort4* __restrict__ dst, int n4) {
    int i = blockIdx.x * blockDim.x + threadIdx.x;
    if (i < n4) {
        float4 v = src[i];
        ushort4 w;
        w.x = f2b(v.x); w.y = f2b(v.y); w.z = f2b(v.z); w.w = f2b(v.w);
        dst[i] = w;
    }
}

// ---------------- gather propagation ----------------
// 16 lanes per node (lane sub = 4 dims via ushort4), 4 nodes per wave.
// acc = (base + a) * accScale  (base = emb for layer 1, acc itself otherwise)
__global__ __launch_bounds__(256) void gather_kernel(
        const int* __restrict__ off, const int2* __restrict__ csr,
        const bf16_t* __restrict__ xb,
        bf16_t* __restrict__ yb,                       // null on last layer
        const float* __restrict__ baseU, const float* __restrict__ baseIadj,
        float* __restrict__ accU, float* __restrict__ accIadj,
        float accScale) {
    int lane = threadIdx.x & 63;
    int g = lane >> 4;
    int sub = lane & 15;
    int n = blockIdx.x * 16 + (threadIdx.x >> 6) * 4 + g;   // N_CNT % 16 == 0
    int s = off[n], e = off[n + 1];
    float4 a = make_float4(0.f, 0.f, 0.f, 0.f);
    int i = s;
    for (; i + 2 <= e; i += 2) {
        int2 p0 = csr[i], p1 = csr[i + 1];
        ushort4 v0 = *(const ushort4*)(xb + ((size_t)p0.x << 6) + sub * 4);
        ushort4 v1 = *(const ushort4*)(xb + ((size_t)p1.x << 6) + sub * 4);
        float n0 = __int_as_float(p0.y), n1 = __int_as_float(p1.y);
        a.x = fmaf(n0, b2f(v0.x), a.x);
        a.y = fmaf(n0, b2f(v0.y), a.y);
        a.z = fmaf(n0, b2f(v0.z), a.z);
        a.w = fmaf(n0, b2f(v0.w), a.w);
        a.x = fmaf(n1, b2f(v1.x), a.x);
        a.y = fmaf(n1, b2f(v1.y), a.y);
        a.z = fmaf(n1, b2f(v1.z), a.z);
        a.w = fmaf(n1, b2f(v1.w), a.w);
    }
    if (i < e) {
        int2 p0 = csr[i];
        ushort4 v0 = *(const ushort4*)(xb + ((size_t)p0.x << 6) + sub * 4);
        float n0 = __int_as_float(p0.y);
        a.x = fmaf(n0, b2f(v0.x), a.x);
        a.y = fmaf(n0, b2f(v0.y), a.y);
        a.z = fmaf(n0, b2f(v0.z), a.z);
        a.w = fmaf(n0, b2f(v0.w), a.w);
    }
    size_t base = ((size_t)n << 6) + sub * 4;
    if (yb) {
        ushort4 w;
        w.x = f2b(a.x); w.y = f2b(a.y); w.z = f2b(a.z); w.w = f2b(a.w);
        *(ushort4*)(yb + base) = w;
    }
    const float* bp = (n < U_CNT ? baseU : baseIadj) + base;
    float*       ap = (n < U_CNT ? accU : accIadj) + base;
    float4 b = *(const float4*)bp;
    float4 r;
    r.x = (b.x + a.x) * accScale;
    r.y = (b.y + a.y) * accScale;
    r.z = (b.z + a.z) * accScale;
    r.w = (b.w + a.w) * accScale;
    *(float4*)ap = r;
}

// ---------------- utility ----------------

__global__ void copy4_kernel(const float4* __restrict__ src, float4* __restrict__ dst, int n) {
    int i = blockIdx.x * blockDim.x + threadIdx.x;
    if (i < n) dst[i] = src[i];
}

// ---------------- host ----------------

extern "C" void kernel_launch(void* const* d_in, const int* in_sizes, int n_in,
                              void* d_out, int out_size, void* d_ws, size_t ws_size,
                              hipStream_t stream) {
    const int*   edge = (const int*)d_in[0];
    const float* embU = (const float*)d_in[1];
    const float* embI = (const float*)d_in[2];
    const int E = in_sizes[0] / 2;
    const int* row = edge;
    const int* col = edge + E;

    float* out  = (float*)d_out;
    float* accU = out;
    float* cu   = out + (size_t)U_CNT * DIM;
    float* accI = out + (size_t)2 * U_CNT * DIM;
    float* ci   = accI + (size_t)I_CNT * DIM;

    // workspace carve-up
    char* ws = (char*)d_ws;
    size_t p = 0;
    bf16_t* xA  = (bf16_t*)(ws + p); p += (size_t)N_CNT * DIM * sizeof(bf16_t);  // 64 MB
    int*    cnt = (int*)(ws + p);    p += ((size_t)N_CNT + 4) * sizeof(int);
    int*    off = (int*)(ws + p);    p += ((size_t)N_CNT + 4) * sizeof(int);
    int*    cur = (int*)(ws + p);    p += ((size_t)N_CNT + 4) * sizeof(int);
    float*  dis = (float*)(ws + p);  p += ((size_t)N_CNT + 4) * sizeof(float);
    int*    bsum= (int*)(ws + p);    p += 1024 * sizeof(int);
    int2*   csr = (int2*)(ws + p);   p += (size_t)E * sizeof(int2);              // 20 MB

    bf16_t* xB = (bf16_t*)cu;   // out-scratch region (76.8 MB) as 2nd bf16 buffer (64 MB)

    const float* embIadj = embI - (size_t)U_CNT * DIM;
    float* accIadj = accI - (size_t)U_CNT * DIM;

    const int B = 256;
    const int nU4 = U_CNT * DIM / 4;
    const int nI4 = I_CNT * DIM / 4;
    const int gU4 = (nU4 + B - 1) / B;
    const int gI4 = (nI4 + B - 1) / B;
    const int gE  = (E + B - 1) / B;
    const int gN  = (N_CNT + B - 1) / B;
    const int gGather = N_CNT / 16;     // 31250, exact

    // 1. degree + normalization
    hipMemsetAsync(cnt, 0, (size_t)N_CNT * sizeof(int), stream);
    deg_cnt_kernel<<<gE, B, 0, stream>>>(col, cnt, E);
    dis_kernel<<<gN, B, 0, stream>>>(cnt, dis, N_CNT);

    // 2. CSR build
    scan1_kernel<<<NB1, 256, 0, stream>>>(cnt, bsum, N_CNT);
    scan2_kernel<<<1, 512, 0, stream>>>(bsum, NB1);
    scan3_kernel<<<NB1, 256, 0, stream>>>(cnt, bsum, off, cur, N_CNT, E);
    fill_kernel<<<gE, B, 0, stream>>>(row, col, dis, cur, csr, E);

    // 3. x0 -> bf16 (xA)
    f2b_kernel<<<gU4, B, 0, stream>>>((const float4*)embU, (ushort4*)xA, nU4);
    f2b_kernel<<<gI4, B, 0, stream>>>((const float4*)embI,
                                      (ushort4*)(xA + (size_t)U_CNT * DIM), nI4);

    // 4. four layers; acc init fused into layer 1; final scale fused into layer 4
    gather_kernel<<<gGather, B, 0, stream>>>(off, csr, xA, xB,
                                             embU, embIadj, accU, accIadj, 1.0f);
    gather_kernel<<<gGather, B, 0, stream>>>(off, csr, xB, xA,
                                             accU, accIadj, accU, accIadj, 1.0f);
    gather_kernel<<<gGather, B, 0, stream>>>(off, csr, xA, xB,
                                             accU, accIadj, accU, accIadj, 1.0f);
    gather_kernel<<<gGather, B, 0, stream>>>(off, csr, xB, nullptr,
                                             accU, accIadj, accU, accIadj, 1.0f / 25.0f);

    // 5. restore verbatim input copies into the scratched output regions
    copy4_kernel<<<gU4, B, 0, stream>>>((const float4*)embU, (float4*)cu, nU4);
    copy4_kernel<<<gI4, B, 0, stream>>>((const float4*)embI, (float4*)ci, nI4);
}

// Round 4
// 639.744 us; speedup vs baseline: 4.4550x; 1.2835x over previous
//
#include <hip/hip_runtime.h>
#include <stdint.h>

#define U_CNT 300000
#define I_CNT 200000
#define N_CNT 500000
#define DIM 64
#define SCAN_CHUNK 1024
#define NB1 ((N_CNT + SCAN_CHUNK - 1) / SCAN_CHUNK)   // 489

typedef unsigned short bf16_t;

__device__ __forceinline__ float lof(uint32_t u) { return __uint_as_float(u << 16); }
__device__ __forceinline__ float hif(uint32_t u) { return __uint_as_float(u & 0xFFFF0000u); }
__device__ __forceinline__ uint32_t rnd_bf(float f) {
    uint32_t u = __float_as_uint(f);
    return u + (0x7FFFu + ((u >> 16) & 1u));      // rne, still in high bits
}
__device__ __forceinline__ uint32_t packbf(float lo, float hi) {
    return (rnd_bf(lo) >> 16) | (rnd_bf(hi) & 0xFFFF0000u);
}
__device__ __forceinline__ bf16_t f2b(float f) { return (bf16_t)(rnd_bf(f) >> 16); }

// ---------------- degree / normalization ----------------

__global__ void deg_cnt_kernel(const int* __restrict__ col, int* __restrict__ cnt, int E) {
    int e = blockIdx.x * blockDim.x + threadIdx.x;
    if (e < E) atomicAdd(&cnt[col[e]], 1);
}

__global__ void dis_kernel(const int* __restrict__ cnt, float* __restrict__ dis, int n) {
    int i = blockIdx.x * blockDim.x + threadIdx.x;
    if (i < n) {
        int d = cnt[i];
        dis[i] = d > 0 ? rsqrtf((float)d) : 0.0f;
    }
}

// ---------------- prefix sum ----------------

__global__ void scan1_kernel(const int* __restrict__ cnt, int* __restrict__ bsum, int n) {
    __shared__ int lds[256];
    int t = threadIdx.x;
    int i = blockIdx.x * SCAN_CHUNK + t * 4;
    int4 v = make_int4(0, 0, 0, 0);
    if (i + 3 < n) v = *(const int4*)(cnt + i);
    else {
        if (i     < n) v.x = cnt[i];
        if (i + 1 < n) v.y = cnt[i + 1];
        if (i + 2 < n) v.z = cnt[i + 2];
        if (i + 3 < n) v.w = cnt[i + 3];
    }
    lds[t] = v.x + v.y + v.z + v.w;
    __syncthreads();
    for (int o = 128; o > 0; o >>= 1) {
        if (t < o) lds[t] += lds[t + o];
        __syncthreads();
    }
    if (t == 0) bsum[blockIdx.x] = lds[0];
}

__global__ void scan2_kernel(int* __restrict__ bsum, int nb) {
    __shared__ int lds[512];
    int t = threadIdx.x;
    int v = (t < nb) ? bsum[t] : 0;
    lds[t] = v;
    __syncthreads();
    for (int o = 1; o < 512; o <<= 1) {
        int a = lds[t] + ((t >= o) ? lds[t - o] : 0);
        __syncthreads();
        lds[t] = a;
        __syncthreads();
    }
    if (t < nb) bsum[t] = lds[t] - v;
}

__global__ void scan3_kernel(const int* __restrict__ cnt, const int* __restrict__ bsum,
                             int* __restrict__ off, int* __restrict__ cur, int n, int E) {
    __shared__ int lds[256];
    int t = threadIdx.x;
    int i = blockIdx.x * SCAN_CHUNK + t * 4;
    int4 v = make_int4(0, 0, 0, 0);
    if (i + 3 < n) v = *(const int4*)(cnt + i);
    else {
        if (i     < n) v.x = cnt[i];
        if (i + 1 < n) v.y = cnt[i + 1];
        if (i + 2 < n) v.z = cnt[i + 2];
        if (i + 3 < n) v.w = cnt[i + 3];
    }
    int s = v.x + v.y + v.z + v.w;
    lds[t] = s;
    __syncthreads();
    for (int o = 1; o < 256; o <<= 1) {
        int a = lds[t] + ((t >= o) ? lds[t - o] : 0);
        __syncthreads();
        lds[t] = a;
        __syncthreads();
    }
    int ex = lds[t] - s + bsum[blockIdx.x];
    int o0 = ex, o1 = ex + v.x, o2 = o1 + v.y, o3 = o2 + v.z;
    if (i     < n) { off[i]     = o0; cur[i]     = o0; }
    if (i + 1 < n) { off[i + 1] = o1; cur[i + 1] = o1; }
    if (i + 2 < n) { off[i + 2] = o2; cur[i + 2] = o2; }
    if (i + 3 < n) { off[i + 3] = o3; cur[i + 3] = o3; }
    if (i == n - 4) off[n] = E;   // N_CNT % 4 == 0
}

__global__ void fill_kernel(const int* __restrict__ row, const int* __restrict__ col,
                            const float* __restrict__ dis, int* __restrict__ cur,
                            int2* __restrict__ csr, int E) {
    int e = blockIdx.x * blockDim.x + threadIdx.x;
    if (e < E) {
        int r = row[e], c = col[e];
        int p = atomicAdd(&cur[c], 1);
        int2 pr;
        pr.x = r;
        pr.y = __float_as_int(dis[r] * dis[c]);
        csr[p] = pr;
    }
}

// ---------------- f32 -> bf16 ----------------

__global__ void f2b_kernel(const float4* __restrict__ src, ushort4* __restrict__ dst, int n4) {
    int i = blockIdx.x * blockDim.x + threadIdx.x;
    if (i < n4) {
        float4 v = src[i];
        ushort4 w;
        w.x = f2b(v.x); w.y = f2b(v.y); w.z = f2b(v.z); w.w = f2b(v.w);
        dst[i] = w;
    }
}

// ---------------- gather propagation ----------------
// 8 lanes per node (uint4 = 8 packed bf16 per lane), 8 nodes per wave.
__global__ __launch_bounds__(256) void gather8_kernel(
        const int* __restrict__ off, const int2* __restrict__ csr,
        const uint32_t* __restrict__ xb, uint4* __restrict__ yb) {
    int lane = threadIdx.x & 63;
    int sub  = lane & 7;
    int n = blockIdx.x * 32 + (threadIdx.x >> 6) * 8 + (lane >> 3);  // N_CNT % 32 == 0
    int s = off[n], e = off[n + 1];
    float a0 = 0, a1 = 0, a2 = 0, a3 = 0, a4 = 0, a5 = 0, a6 = 0, a7 = 0;
    int i = s;
    for (; i + 2 <= e; i += 2) {
        int2 p0 = csr[i], p1 = csr[i + 1];
        uint4 v0 = *((const uint4*)(xb + ((size_t)p0.x << 5)) + sub);
        uint4 v1 = *((const uint4*)(xb + ((size_t)p1.x << 5)) + sub);
        float n0 = __int_as_float(p0.y), n1 = __int_as_float(p1.y);
        a0 = fmaf(n0, lof(v0.x), a0); a1 = fmaf(n0, hif(v0.x), a1);
        a2 = fmaf(n0, lof(v0.y), a2); a3 = fmaf(n0, hif(v0.y), a3);
        a4 = fmaf(n0, lof(v0.z), a4); a5 = fmaf(n0, hif(v0.z), a5);
        a6 = fmaf(n0, lof(v0.w), a6); a7 = fmaf(n0, hif(v0.w), a7);
        a0 = fmaf(n1, lof(v1.x), a0); a1 = fmaf(n1, hif(v1.x), a1);
        a2 = fmaf(n1, lof(v1.y), a2); a3 = fmaf(n1, hif(v1.y), a3);
        a4 = fmaf(n1, lof(v1.z), a4); a5 = fmaf(n1, hif(v1.z), a5);
        a6 = fmaf(n1, lof(v1.w), a6); a7 = fmaf(n1, hif(v1.w), a7);
    }
    if (i < e) {
        int2 p0 = csr[i];
        uint4 v0 = *((const uint4*)(xb + ((size_t)p0.x << 5)) + sub);
        float n0 = __int_as_float(p0.y);
        a0 = fmaf(n0, lof(v0.x), a0); a1 = fmaf(n0, hif(v0.x), a1);
        a2 = fmaf(n0, lof(v0.y), a2); a3 = fmaf(n0, hif(v0.y), a3);
        a4 = fmaf(n0, lof(v0.z), a4); a5 = fmaf(n0, hif(v0.z), a5);
        a6 = fmaf(n0, lof(v0.w), a6); a7 = fmaf(n0, hif(v0.w), a7);
    }
    uint4 w;
    w.x = packbf(a0, a1); w.y = packbf(a2, a3);
    w.z = packbf(a4, a5); w.w = packbf(a6, a7);
    yb[(size_t)n * 8 + sub] = w;
}

// ---------------- fused finalize: fin = (emb + y1+y2+y3+y4)/25, cpy = emb ----------------

__global__ void final_kernel(const float4* __restrict__ emb,
                             const uint2* __restrict__ y1, const uint2* __restrict__ y2,
                             const uint2* __restrict__ y3, const uint2* __restrict__ y4,
                             float4* __restrict__ fin, float4* __restrict__ cpy, int n4) {
    int i = blockIdx.x * blockDim.x + threadIdx.x;
    if (i >= n4) return;
    float4 b = emb[i];
    uint2 u1 = y1[i], u2 = y2[i], u3 = y3[i], u4 = y4[i];
    float4 s;
    s.x = b.x + lof(u1.x) + lof(u2.x) + lof(u3.x) + lof(u4.x);
    s.y = b.y + hif(u1.x) + hif(u2.x) + hif(u3.x) + hif(u4.x);
    s.z = b.z + lof(u1.y) + lof(u2.y) + lof(u3.y) + lof(u4.y);
    s.w = b.w + hif(u1.y) + hif(u2.y) + hif(u3.y) + hif(u4.y);
    const float k = 1.0f / 25.0f;
    float4 r;
    r.x = s.x * k; r.y = s.y * k; r.z = s.z * k; r.w = s.w * k;
    fin[i] = r;
    cpy[i] = b;
}

// ---------------- host ----------------

extern "C" void kernel_launch(void* const* d_in, const int* in_sizes, int n_in,
                              void* d_out, int out_size, void* d_ws, size_t ws_size,
                              hipStream_t stream) {
    const int*   edge = (const int*)d_in[0];
    const float* embU = (const float*)d_in[1];
    const float* embI = (const float*)d_in[2];
    const int E = in_sizes[0] / 2;
    const int* row = edge;
    const int* col = edge + E;

    float* out  = (float*)d_out;
    float* accU = out;
    float* cu   = out + (size_t)U_CNT * DIM;
    float* accI = out + (size_t)2 * U_CNT * DIM;
    float* ci   = accI + (size_t)I_CNT * DIM;

    // workspace carve-up (ws ~1 GB; we use ~350 MB)
    const size_t XB = (size_t)N_CNT * DIM * sizeof(bf16_t);   // 64 MB
    char* ws = (char*)d_ws;
    size_t p = 0;
    bf16_t* x0 = (bf16_t*)(ws + p); p += XB;
    bf16_t* y1 = (bf16_t*)(ws + p); p += XB;
    bf16_t* y2 = (bf16_t*)(ws + p); p += XB;
    bf16_t* y3 = (bf16_t*)(ws + p); p += XB;
    bf16_t* y4 = (bf16_t*)(ws + p); p += XB;
    int*   cnt  = (int*)(ws + p);   p += ((size_t)N_CNT + 4) * sizeof(int);
    int*   off  = (int*)(ws + p);   p += ((size_t)N_CNT + 4) * sizeof(int);
    int*   cur  = (int*)(ws + p);   p += ((size_t)N_CNT + 4) * sizeof(int);
    float* dis  = (float*)(ws + p); p += ((size_t)N_CNT + 4) * sizeof(float);
    int*   bsum = (int*)(ws + p);   p += 1024 * sizeof(int);
    int2*  csr  = (int2*)(ws + p);  p += (size_t)E * sizeof(int2);              // 20 MB

    const int B = 256;
    const int nU4 = U_CNT * DIM / 4;
    const int nI4 = I_CNT * DIM / 4;
    const int gU4 = (nU4 + B - 1) / B;
    const int gI4 = (nI4 + B - 1) / B;
    const int gE  = (E + B - 1) / B;
    const int gN  = (N_CNT + B - 1) / B;
    const int gGather = N_CNT / 32;     // 15625, exact

    // 1. degree + normalization
    hipMemsetAsync(cnt, 0, (size_t)N_CNT * sizeof(int), stream);
    deg_cnt_kernel<<<gE, B, 0, stream>>>(col, cnt, E);
    dis_kernel<<<gN, B, 0, stream>>>(cnt, dis, N_CNT);

    // 2. CSR build
    scan1_kernel<<<NB1, 256, 0, stream>>>(cnt, bsum, N_CNT);
    scan2_kernel<<<1, 512, 0, stream>>>(bsum, NB1);
    scan3_kernel<<<NB1, 256, 0, stream>>>(cnt, bsum, off, cur, N_CNT, E);
    fill_kernel<<<gE, B, 0, stream>>>(row, col, dis, cur, csr, E);

    // 3. x0 -> bf16
    f2b_kernel<<<gU4, B, 0, stream>>>((const float4*)embU, (ushort4*)x0, nU4);
    f2b_kernel<<<gI4, B, 0, stream>>>((const float4*)embI,
                                      (ushort4*)(x0 + (size_t)U_CNT * DIM), nI4);

    // 4. four propagation layers, each writing its own bf16 y buffer
    gather8_kernel<<<gGather, B, 0, stream>>>(off, csr, (const uint32_t*)x0, (uint4*)y1);
    gather8_kernel<<<gGather, B, 0, stream>>>(off, csr, (const uint32_t*)y1, (uint4*)y2);
    gather8_kernel<<<gGather, B, 0, stream>>>(off, csr, (const uint32_t*)y2, (uint4*)y3);
    gather8_kernel<<<gGather, B, 0, stream>>>(off, csr, (const uint32_t*)y3, (uint4*)y4);

    // 5. fused finalize + verbatim copies (users then items)
    const size_t iOff = (size_t)U_CNT * (DIM / 4);   // item offset in uint2 units
    final_kernel<<<gU4, B, 0, stream>>>((const float4*)embU,
        (const uint2*)y1, (const uint2*)y2, (const uint2*)y3, (const uint2*)y4,
        (float4*)accU, (float4*)cu, nU4);
    final_kernel<<<gI4, B, 0, stream>>>((const float4*)embI,
        (const uint2*)y1 + iOff, (const uint2*)y2 + iOff,
        (const uint2*)y3 + iOff, (const uint2*)y4 + iOff,
        (float4*)accI, (float4*)ci, nI4);
}

// Round 5
// 632.260 us; speedup vs baseline: 4.5077x; 1.0118x over previous
//
#include <hip/hip_runtime.h>
#include <stdint.h>

#define U_CNT 300000
#define I_CNT 200000
#define N_CNT 500000
#define DIM 64
#define SCAN_CHUNK 1024
#define NB1 ((N_CNT + SCAN_CHUNK - 1) / SCAN_CHUNK)   // 489

typedef unsigned short bf16_t;

__device__ __forceinline__ float lof(uint32_t u) { return __uint_as_float(u << 16); }
__device__ __forceinline__ float hif(uint32_t u) { return __uint_as_float(u & 0xFFFF0000u); }
__device__ __forceinline__ uint32_t rnd_bf(float f) {
    uint32_t u = __float_as_uint(f);
    return u + (0x7FFFu + ((u >> 16) & 1u));      // rne, still in high bits
}
__device__ __forceinline__ uint32_t packbf(float lo, float hi) {
    return (rnd_bf(lo) >> 16) | (rnd_bf(hi) & 0xFFFF0000u);
}
__device__ __forceinline__ bf16_t f2b(float f) { return (bf16_t)(rnd_bf(f) >> 16); }

// ---------------- degree / normalization ----------------

__global__ void deg_cnt_kernel(const int* __restrict__ col, int* __restrict__ cnt, int E) {
    int e = blockIdx.x * blockDim.x + threadIdx.x;
    if (e < E) atomicAdd(&cnt[col[e]], 1);
}

__global__ void dis_kernel(const int* __restrict__ cnt, float* __restrict__ dis, int n) {
    int i = blockIdx.x * blockDim.x + threadIdx.x;
    if (i < n) {
        int d = cnt[i];
        dis[i] = d > 0 ? rsqrtf((float)d) : 0.0f;
    }
}

// ---------------- prefix sum ----------------

__global__ void scan1_kernel(const int* __restrict__ cnt, int* __restrict__ bsum, int n) {
    __shared__ int lds[256];
    int t = threadIdx.x;
    int i = blockIdx.x * SCAN_CHUNK + t * 4;
    int4 v = make_int4(0, 0, 0, 0);
    if (i + 3 < n) v = *(const int4*)(cnt + i);
    else {
        if (i     < n) v.x = cnt[i];
        if (i + 1 < n) v.y = cnt[i + 1];
        if (i + 2 < n) v.z = cnt[i + 2];
        if (i + 3 < n) v.w = cnt[i + 3];
    }
    lds[t] = v.x + v.y + v.z + v.w;
    __syncthreads();
    for (int o = 128; o > 0; o >>= 1) {
        if (t < o) lds[t] += lds[t + o];
        __syncthreads();
    }
    if (t == 0) bsum[blockIdx.x] = lds[0];
}

__global__ void scan2_kernel(int* __restrict__ bsum, int nb) {
    __shared__ int lds[512];
    int t = threadIdx.x;
    int v = (t < nb) ? bsum[t] : 0;
    lds[t] = v;
    __syncthreads();
    for (int o = 1; o < 512; o <<= 1) {
        int a = lds[t] + ((t >= o) ? lds[t - o] : 0);
        __syncthreads();
        lds[t] = a;
        __syncthreads();
    }
    if (t < nb) bsum[t] = lds[t] - v;
}

__global__ void scan3_kernel(const int* __restrict__ cnt, const int* __restrict__ bsum,
                             int* __restrict__ off, int* __restrict__ cur, int n, int E) {
    __shared__ int lds[256];
    int t = threadIdx.x;
    int i = blockIdx.x * SCAN_CHUNK + t * 4;
    int4 v = make_int4(0, 0, 0, 0);
    if (i + 3 < n) v = *(const int4*)(cnt + i);
    else {
        if (i     < n) v.x = cnt[i];
        if (i + 1 < n) v.y = cnt[i + 1];
        if (i + 2 < n) v.z = cnt[i + 2];
        if (i + 3 < n) v.w = cnt[i + 3];
    }
    int s = v.x + v.y + v.z + v.w;
    lds[t] = s;
    __syncthreads();
    for (int o = 1; o < 256; o <<= 1) {
        int a = lds[t] + ((t >= o) ? lds[t - o] : 0);
        __syncthreads();
        lds[t] = a;
        __syncthreads();
    }
    int ex = lds[t] - s + bsum[blockIdx.x];
    int o0 = ex, o1 = ex + v.x, o2 = o1 + v.y, o3 = o2 + v.z;
    if (i     < n) { off[i]     = o0; cur[i]     = o0; }
    if (i + 1 < n) { off[i + 1] = o1; cur[i + 1] = o1; }
    if (i + 2 < n) { off[i + 2] = o2; cur[i + 2] = o2; }
    if (i + 3 < n) { off[i + 3] = o3; cur[i + 3] = o3; }
    if (i == n - 4) off[n] = E;   // N_CNT % 4 == 0
}

__global__ void fill_kernel(const int* __restrict__ row, const int* __restrict__ col,
                            const float* __restrict__ dis, int* __restrict__ cur,
                            int2* __restrict__ csr, int E) {
    int e = blockIdx.x * blockDim.x + threadIdx.x;
    if (e < E) {
        int r = row[e], c = col[e];
        int p = atomicAdd(&cur[c], 1);
        int2 pr;
        pr.x = r;
        pr.y = __float_as_int(dis[r] * dis[c]);
        csr[p] = pr;
    }
}

// ---------------- f32 -> bf16 ----------------

__global__ void f2b_kernel(const float4* __restrict__ src, ushort4* __restrict__ dst, int n4) {
    int i = blockIdx.x * blockDim.x + threadIdx.x;
    if (i < n4) {
        float4 v = src[i];
        ushort4 w;
        w.x = f2b(v.x); w.y = f2b(v.y); w.z = f2b(v.z); w.w = f2b(v.w);
        dst[i] = w;
    }
}

// ---------------- gather propagation (2-stage software pipeline) ----------------
// 8 lanes per node (uint4 = 8 packed bf16 per lane), 8 nodes per wave.
// Pipeline: while FMA-ing pair k, x-loads for pair k+1 and csr-loads for pair k+2
// are in flight. Invalid slots load row 0 with norm=0 (branchless, no NaN risk).
__global__ __launch_bounds__(256) void gather8_kernel(
        const int* __restrict__ off, const int2* __restrict__ csr,
        const uint32_t* __restrict__ xb, uint4* __restrict__ yb, int nE) {
    int lane = threadIdx.x & 63;
    int sub  = lane & 7;
    int n = blockIdx.x * 32 + (threadIdx.x >> 6) * 8 + (lane >> 3);  // N_CNT % 32 == 0
    int s = off[n], e = off[n + 1];
    const uint4* xv = (const uint4*)xb;

    float a0 = 0, a1 = 0, a2 = 0, a3 = 0, a4 = 0, a5 = 0, a6 = 0, a7 = 0;

    int i0 = s;
    // ---- prologue: csr + x for pair 0, csr for pair 1 ----
    int2 pa = csr[(i0     < nE) ? i0     : (nE - 1)];
    int2 pb = csr[(i0 + 1 < nE) ? i0 + 1 : (nE - 1)];
    float na = (i0     < e) ? __int_as_float(pa.y) : 0.0f;
    float nb = (i0 + 1 < e) ? __int_as_float(pb.y) : 0.0f;
    int   ra = (i0     < e) ? pa.x : 0;
    int   rb = (i0 + 1 < e) ? pb.x : 0;
    uint4 va = xv[((size_t)ra << 3) + sub];
    uint4 vb = xv[((size_t)rb << 3) + sub];
    int i1 = i0 + 2;
    int2 qa = csr[(i1     < nE) ? i1     : (nE - 1)];
    int2 qb = csr[(i1 + 1 < nE) ? i1 + 1 : (nE - 1)];

    while (i0 < e) {
        // issue x loads for next pair (csr regs from last iteration)
        float ma = (i1     < e) ? __int_as_float(qa.y) : 0.0f;
        float mb = (i1 + 1 < e) ? __int_as_float(qb.y) : 0.0f;
        int   sa = (i1     < e) ? qa.x : 0;
        int   sb = (i1 + 1 < e) ? qb.x : 0;
        uint4 wa = xv[((size_t)sa << 3) + sub];
        uint4 wb = xv[((size_t)sb << 3) + sub];
        // issue csr loads two pairs ahead
        int i2 = i1 + 2;
        qa = csr[(i2     < nE) ? i2     : (nE - 1)];
        qb = csr[(i2 + 1 < nE) ? i2 + 1 : (nE - 1)];
        // FMA current pair (waits only on va/vb issued one iteration ago)
        a0 = fmaf(na, lof(va.x), a0); a1 = fmaf(na, hif(va.x), a1);
        a2 = fmaf(na, lof(va.y), a2); a3 = fmaf(na, hif(va.y), a3);
        a4 = fmaf(na, lof(va.z), a4); a5 = fmaf(na, hif(va.z), a5);
        a6 = fmaf(na, lof(va.w), a6); a7 = fmaf(na, hif(va.w), a7);
        a0 = fmaf(nb, lof(vb.x), a0); a1 = fmaf(nb, hif(vb.x), a1);
        a2 = fmaf(nb, lof(vb.y), a2); a3 = fmaf(nb, hif(vb.y), a3);
        a4 = fmaf(nb, lof(vb.z), a4); a5 = fmaf(nb, hif(vb.z), a5);
        a6 = fmaf(nb, lof(vb.w), a6); a7 = fmaf(nb, hif(vb.w), a7);
        // rotate stages
        va = wa; vb = wb; na = ma; nb = mb;
        i0 = i1; i1 = i2;
    }

    uint4 w;
    w.x = packbf(a0, a1); w.y = packbf(a2, a3);
    w.z = packbf(a4, a5); w.w = packbf(a6, a7);
    yb[((size_t)n << 3) + sub] = w;
}

// ---------------- fused finalize: fin = (emb + y1+y2+y3+y4)/25, cpy = emb ----------------

__global__ void final_kernel(const float4* __restrict__ emb,
                             const uint2* __restrict__ y1, const uint2* __restrict__ y2,
                             const uint2* __restrict__ y3, const uint2* __restrict__ y4,
                             float4* __restrict__ fin, float4* __restrict__ cpy, int n4) {
    int i = blockIdx.x * blockDim.x + threadIdx.x;
    if (i >= n4) return;
    float4 b = emb[i];
    uint2 u1 = y1[i], u2 = y2[i], u3 = y3[i], u4 = y4[i];
    float4 s;
    s.x = b.x + lof(u1.x) + lof(u2.x) + lof(u3.x) + lof(u4.x);
    s.y = b.y + hif(u1.x) + hif(u2.x) + hif(u3.x) + hif(u4.x);
    s.z = b.z + lof(u1.y) + lof(u2.y) + lof(u3.y) + lof(u4.y);
    s.w = b.w + hif(u1.y) + hif(u2.y) + hif(u3.y) + hif(u4.y);
    const float k = 1.0f / 25.0f;
    float4 r;
    r.x = s.x * k; r.y = s.y * k; r.z = s.z * k; r.w = s.w * k;
    fin[i] = r;
    cpy[i] = b;
}

// ---------------- host ----------------

extern "C" void kernel_launch(void* const* d_in, const int* in_sizes, int n_in,
                              void* d_out, int out_size, void* d_ws, size_t ws_size,
                              hipStream_t stream) {
    const int*   edge = (const int*)d_in[0];
    const float* embU = (const float*)d_in[1];
    const float* embI = (const float*)d_in[2];
    const int E = in_sizes[0] / 2;
    const int* row = edge;
    const int* col = edge + E;

    float* out  = (float*)d_out;
    float* accU = out;
    float* cu   = out + (size_t)U_CNT * DIM;
    float* accI = out + (size_t)2 * U_CNT * DIM;
    float* ci   = accI + (size_t)I_CNT * DIM;

    // workspace carve-up (ws ~1 GB; we use ~350 MB)
    const size_t XB = (size_t)N_CNT * DIM * sizeof(bf16_t);   // 64 MB
    char* ws = (char*)d_ws;
    size_t p = 0;
    bf16_t* x0 = (bf16_t*)(ws + p); p += XB;
    bf16_t* y1 = (bf16_t*)(ws + p); p += XB;
    bf16_t* y2 = (bf16_t*)(ws + p); p += XB;
    bf16_t* y3 = (bf16_t*)(ws + p); p += XB;
    bf16_t* y4 = (bf16_t*)(ws + p); p += XB;
    int*   cnt  = (int*)(ws + p);   p += ((size_t)N_CNT + 4) * sizeof(int);
    int*   off  = (int*)(ws + p);   p += ((size_t)N_CNT + 4) * sizeof(int);
    int*   cur  = (int*)(ws + p);   p += ((size_t)N_CNT + 4) * sizeof(int);
    float* dis  = (float*)(ws + p); p += ((size_t)N_CNT + 4) * sizeof(float);
    int*   bsum = (int*)(ws + p);   p += 1024 * sizeof(int);
    int2*  csr  = (int2*)(ws + p);  p += (size_t)E * sizeof(int2);              // 20 MB

    const int B = 256;
    const int nU4 = U_CNT * DIM / 4;
    const int nI4 = I_CNT * DIM / 4;
    const int gU4 = (nU4 + B - 1) / B;
    const int gI4 = (nI4 + B - 1) / B;
    const int gE  = (E + B - 1) / B;
    const int gN  = (N_CNT + B - 1) / B;
    const int gGather = N_CNT / 32;     // 15625, exact

    // 1. degree + normalization
    hipMemsetAsync(cnt, 0, (size_t)N_CNT * sizeof(int), stream);
    deg_cnt_kernel<<<gE, B, 0, stream>>>(col, cnt, E);
    dis_kernel<<<gN, B, 0, stream>>>(cnt, dis, N_CNT);

    // 2. CSR build
    scan1_kernel<<<NB1, 256, 0, stream>>>(cnt, bsum, N_CNT);
    scan2_kernel<<<1, 512, 0, stream>>>(bsum, NB1);
    scan3_kernel<<<NB1, 256, 0, stream>>>(cnt, bsum, off, cur, N_CNT, E);
    fill_kernel<<<gE, B, 0, stream>>>(row, col, dis, cur, csr, E);

    // 3. x0 -> bf16
    f2b_kernel<<<gU4, B, 0, stream>>>((const float4*)embU, (ushort4*)x0, nU4);
    f2b_kernel<<<gI4, B, 0, stream>>>((const float4*)embI,
                                      (ushort4*)(x0 + (size_t)U_CNT * DIM), nI4);

    // 4. four propagation layers, each writing its own bf16 y buffer
    gather8_kernel<<<gGather, B, 0, stream>>>(off, csr, (const uint32_t*)x0, (uint4*)y1, E);
    gather8_kernel<<<gGather, B, 0, stream>>>(off, csr, (const uint32_t*)y1, (uint4*)y2, E);
    gather8_kernel<<<gGather, B, 0, stream>>>(off, csr, (const uint32_t*)y2, (uint4*)y3, E);
    gather8_kernel<<<gGather, B, 0, stream>>>(off, csr, (const uint32_t*)y3, (uint4*)y4, E);

    // 5. fused finalize + verbatim copies (users then items)
    const size_t iOff = (size_t)U_CNT * (DIM / 4);   // item offset in uint2 units
    final_kernel<<<gU4, B, 0, stream>>>((const float4*)embU,
        (const uint2*)y1, (const uint2*)y2, (const uint2*)y3, (const uint2*)y4,
        (float4*)accU, (float4*)cu, nU4);
    final_kernel<<<gI4, B, 0, stream>>>((const float4*)embI,
        (const uint2*)y1 + iOff, (const uint2*)y2 + iOff,
        (const uint2*)y3 + iOff, (const uint2*)y4 + iOff,
        (float4*)accI, (float4*)ci, nI4);
}

// Round 6
// 599.185 us; speedup vs baseline: 4.7566x; 1.0552x over previous
//
#include <hip/hip_runtime.h>
#include <stdint.h>

#define U_CNT 300000
#define I_CNT 200000
#define N_CNT 500000
#define DIM 64
#define SCAN_CHUNK 1024
#define NB1 ((N_CNT + SCAN_CHUNK - 1) / SCAN_CHUNK)   // 489

typedef unsigned short bf16_t;

__device__ __forceinline__ float lof(uint32_t u) { return __uint_as_float(u << 16); }
__device__ __forceinline__ float hif(uint32_t u) { return __uint_as_float(u & 0xFFFF0000u); }
__device__ __forceinline__ uint32_t rnd_bf(float f) {
    uint32_t u = __float_as_uint(f);
    return u + (0x7FFFu + ((u >> 16) & 1u));      // rne, still in high bits
}
__device__ __forceinline__ uint32_t packbf(float lo, float hi) {
    return (rnd_bf(lo) >> 16) | (rnd_bf(hi) & 0xFFFF0000u);
}
__device__ __forceinline__ bf16_t f2b(float f) { return (bf16_t)(rnd_bf(f) >> 16); }

// ---------------- degree / normalization ----------------

__global__ void deg_cnt_kernel(const int* __restrict__ col, int* __restrict__ cnt, int E) {
    int e = blockIdx.x * blockDim.x + threadIdx.x;
    if (e < E) atomicAdd(&cnt[col[e]], 1);
}

__global__ void dis_kernel(const int* __restrict__ cnt, float* __restrict__ dis, int n) {
    int i = blockIdx.x * blockDim.x + threadIdx.x;
    if (i < n) {
        int d = cnt[i];
        dis[i] = d > 0 ? rsqrtf((float)d) : 0.0f;
    }
}

// ---------------- prefix sum ----------------

__global__ void scan1_kernel(const int* __restrict__ cnt, int* __restrict__ bsum, int n) {
    __shared__ int lds[256];
    int t = threadIdx.x;
    int i = blockIdx.x * SCAN_CHUNK + t * 4;
    int4 v = make_int4(0, 0, 0, 0);
    if (i + 3 < n) v = *(const int4*)(cnt + i);
    else {
        if (i     < n) v.x = cnt[i];
        if (i + 1 < n) v.y = cnt[i + 1];
        if (i + 2 < n) v.z = cnt[i + 2];
        if (i + 3 < n) v.w = cnt[i + 3];
    }
    lds[t] = v.x + v.y + v.z + v.w;
    __syncthreads();
    for (int o = 128; o > 0; o >>= 1) {
        if (t < o) lds[t] += lds[t + o];
        __syncthreads();
    }
    if (t == 0) bsum[blockIdx.x] = lds[0];
}

__global__ void scan2_kernel(int* __restrict__ bsum, int nb) {
    __shared__ int lds[512];
    int t = threadIdx.x;
    int v = (t < nb) ? bsum[t] : 0;
    lds[t] = v;
    __syncthreads();
    for (int o = 1; o < 512; o <<= 1) {
        int a = lds[t] + ((t >= o) ? lds[t - o] : 0);
        __syncthreads();
        lds[t] = a;
        __syncthreads();
    }
    if (t < nb) bsum[t] = lds[t] - v;
}

__global__ void scan3_kernel(const int* __restrict__ cnt, const int* __restrict__ bsum,
                             int* __restrict__ off, int* __restrict__ cur, int n, int E) {
    __shared__ int lds[256];
    int t = threadIdx.x;
    int i = blockIdx.x * SCAN_CHUNK + t * 4;
    int4 v = make_int4(0, 0, 0, 0);
    if (i + 3 < n) v = *(const int4*)(cnt + i);
    else {
        if (i     < n) v.x = cnt[i];
        if (i + 1 < n) v.y = cnt[i + 1];
        if (i + 2 < n) v.z = cnt[i + 2];
        if (i + 3 < n) v.w = cnt[i + 3];
    }
    int s = v.x + v.y + v.z + v.w;
    lds[t] = s;
    __syncthreads();
    for (int o = 1; o < 256; o <<= 1) {
        int a = lds[t] + ((t >= o) ? lds[t - o] : 0);
        __syncthreads();
        lds[t] = a;
        __syncthreads();
    }
    int ex = lds[t] - s + bsum[blockIdx.x];
    int o0 = ex, o1 = ex + v.x, o2 = o1 + v.y, o3 = o2 + v.z;
    if (i     < n) { off[i]     = o0; cur[i]     = o0; }
    if (i + 1 < n) { off[i + 1] = o1; cur[i + 1] = o1; }
    if (i + 2 < n) { off[i + 2] = o2; cur[i + 2] = o2; }
    if (i + 3 < n) { off[i + 3] = o3; cur[i + 3] = o3; }
    if (i == n - 4) off[n] = E;   // N_CNT % 4 == 0
}

__global__ void fill_kernel(const int* __restrict__ row, const int* __restrict__ col,
                            const float* __restrict__ dis, int* __restrict__ cur,
                            int2* __restrict__ csr, int E) {
    int e = blockIdx.x * blockDim.x + threadIdx.x;
    if (e < E) {
        int r = row[e], c = col[e];
        int p = atomicAdd(&cur[c], 1);
        int2 pr;
        pr.x = r;
        pr.y = __float_as_int(dis[r] * dis[c]);
        csr[p] = pr;
    }
}

// ---------------- f32 -> bf16 ----------------

__global__ void f2b_kernel(const float4* __restrict__ src, ushort4* __restrict__ dst, int n4) {
    int i = blockIdx.x * blockDim.x + threadIdx.x;
    if (i < n4) {
        float4 v = src[i];
        ushort4 w;
        w.x = f2b(v.x); w.y = f2b(v.y); w.z = f2b(v.z); w.w = f2b(v.w);
        dst[i] = w;
    }
}

// ---------------- gather propagation (layers 1..3) ----------------
// 8 lanes per node (uint4 = 8 packed bf16 per lane), 8 nodes per wave.
__global__ __launch_bounds__(256) void gather8_kernel(
        const int* __restrict__ off, const int2* __restrict__ csr,
        const uint32_t* __restrict__ xb, uint4* __restrict__ yb, int nE) {
    int lane = threadIdx.x & 63;
    int sub  = lane & 7;
    int n = blockIdx.x * 32 + (threadIdx.x >> 6) * 8 + (lane >> 3);  // N_CNT % 32 == 0
    int s = off[n], e = off[n + 1];
    const uint4* xv = (const uint4*)xb;

    float a0 = 0, a1 = 0, a2 = 0, a3 = 0, a4 = 0, a5 = 0, a6 = 0, a7 = 0;

    int i0 = s;
    int2 pa = csr[(i0     < nE) ? i0     : (nE - 1)];
    int2 pb = csr[(i0 + 1 < nE) ? i0 + 1 : (nE - 1)];
    float na = (i0     < e) ? __int_as_float(pa.y) : 0.0f;
    float nb = (i0 + 1 < e) ? __int_as_float(pb.y) : 0.0f;
    int   ra = (i0     < e) ? pa.x : 0;
    int   rb = (i0 + 1 < e) ? pb.x : 0;
    uint4 va = xv[((size_t)ra << 3) + sub];
    uint4 vb = xv[((size_t)rb << 3) + sub];
    int i1 = i0 + 2;
    int2 qa = csr[(i1     < nE) ? i1     : (nE - 1)];
    int2 qb = csr[(i1 + 1 < nE) ? i1 + 1 : (nE - 1)];

    while (i0 < e) {
        float ma = (i1     < e) ? __int_as_float(qa.y) : 0.0f;
        float mb = (i1 + 1 < e) ? __int_as_float(qb.y) : 0.0f;
        int   sa = (i1     < e) ? qa.x : 0;
        int   sb = (i1 + 1 < e) ? qb.x : 0;
        uint4 wa = xv[((size_t)sa << 3) + sub];
        uint4 wb = xv[((size_t)sb << 3) + sub];
        int i2 = i1 + 2;
        qa = csr[(i2     < nE) ? i2     : (nE - 1)];
        qb = csr[(i2 + 1 < nE) ? i2 + 1 : (nE - 1)];
        a0 = fmaf(na, lof(va.x), a0); a1 = fmaf(na, hif(va.x), a1);
        a2 = fmaf(na, lof(va.y), a2); a3 = fmaf(na, hif(va.y), a3);
        a4 = fmaf(na, lof(va.z), a4); a5 = fmaf(na, hif(va.z), a5);
        a6 = fmaf(na, lof(va.w), a6); a7 = fmaf(na, hif(va.w), a7);
        a0 = fmaf(nb, lof(vb.x), a0); a1 = fmaf(nb, hif(vb.x), a1);
        a2 = fmaf(nb, lof(vb.y), a2); a3 = fmaf(nb, hif(vb.y), a3);
        a4 = fmaf(nb, lof(vb.z), a4); a5 = fmaf(nb, hif(vb.z), a5);
        a6 = fmaf(nb, lof(vb.w), a6); a7 = fmaf(nb, hif(vb.w), a7);
        va = wa; vb = wb; na = ma; nb = mb;
        i0 = i1; i1 = i2;
    }

    uint4 w;
    w.x = packbf(a0, a1); w.y = packbf(a2, a3);
    w.z = packbf(a4, a5); w.w = packbf(a6, a7);
    yb[((size_t)n << 3) + sub] = w;
}

// ---------------- fused layer-4 gather + finalize + verbatim copy ----------------
// a = gather(y3); fin = (emb + y1 + y2 + y3 + a)/25; cpy = emb.  y4 never materialized.
__global__ __launch_bounds__(256) void gather_final_kernel(
        const int* __restrict__ off, const int2* __restrict__ csr,
        const uint32_t* __restrict__ xb,              // y3 (bf16-packed)
        const uint4* __restrict__ y1, const uint4* __restrict__ y2,
        const float* __restrict__ embU, const float* __restrict__ embIadj,
        float* __restrict__ finU, float* __restrict__ finIadj,
        float* __restrict__ cpyU, float* __restrict__ cpyIadj, int nE) {
    int lane = threadIdx.x & 63;
    int sub  = lane & 7;
    int n = blockIdx.x * 32 + (threadIdx.x >> 6) * 8 + (lane >> 3);
    int s = off[n], e = off[n + 1];
    const uint4* xv = (const uint4*)xb;

    // independent streaming loads: issue up front so they overlap the gather loop
    size_t nodeOff = ((size_t)n << 3) + sub;            // uint4 index into y buffers
    size_t fbase   = ((size_t)n << 6) + (size_t)sub * 8; // float index (8 per lane)
    const float* embP = (n < U_CNT ? embU : embIadj) + fbase;
    float*       finP = (n < U_CNT ? finU : finIadj) + fbase;
    float*       cpyP = (n < U_CNT ? cpyU : cpyIadj) + fbase;
    float4 b0 = *(const float4*)embP;
    float4 b1 = *(const float4*)(embP + 4);
    uint4 u1 = y1[nodeOff];
    uint4 u2 = y2[nodeOff];
    uint4 u3 = xv[nodeOff];                              // y3 row of this node

    float a0 = 0, a1 = 0, a2 = 0, a3 = 0, a4 = 0, a5 = 0, a6 = 0, a7 = 0;

    int i0 = s;
    int2 pa = csr[(i0     < nE) ? i0     : (nE - 1)];
    int2 pb = csr[(i0 + 1 < nE) ? i0 + 1 : (nE - 1)];
    float na = (i0     < e) ? __int_as_float(pa.y) : 0.0f;
    float nb = (i0 + 1 < e) ? __int_as_float(pb.y) : 0.0f;
    int   ra = (i0     < e) ? pa.x : 0;
    int   rb = (i0 + 1 < e) ? pb.x : 0;
    uint4 va = xv[((size_t)ra << 3) + sub];
    uint4 vb = xv[((size_t)rb << 3) + sub];
    int i1 = i0 + 2;
    int2 qa = csr[(i1     < nE) ? i1     : (nE - 1)];
    int2 qb = csr[(i1 + 1 < nE) ? i1 + 1 : (nE - 1)];

    while (i0 < e) {
        float ma = (i1     < e) ? __int_as_float(qa.y) : 0.0f;
        float mb = (i1 + 1 < e) ? __int_as_float(qb.y) : 0.0f;
        int   sa = (i1     < e) ? qa.x : 0;
        int   sb = (i1 + 1 < e) ? qb.x : 0;
        uint4 wa = xv[((size_t)sa << 3) + sub];
        uint4 wb = xv[((size_t)sb << 3) + sub];
        int i2 = i1 + 2;
        qa = csr[(i2     < nE) ? i2     : (nE - 1)];
        qb = csr[(i2 + 1 < nE) ? i2 + 1 : (nE - 1)];
        a0 = fmaf(na, lof(va.x), a0); a1 = fmaf(na, hif(va.x), a1);
        a2 = fmaf(na, lof(va.y), a2); a3 = fmaf(na, hif(va.y), a3);
        a4 = fmaf(na, lof(va.z), a4); a5 = fmaf(na, hif(va.z), a5);
        a6 = fmaf(na, lof(va.w), a6); a7 = fmaf(na, hif(va.w), a7);
        a0 = fmaf(nb, lof(vb.x), a0); a1 = fmaf(nb, hif(vb.x), a1);
        a2 = fmaf(nb, lof(vb.y), a2); a3 = fmaf(nb, hif(vb.y), a3);
        a4 = fmaf(nb, lof(vb.z), a4); a5 = fmaf(nb, hif(vb.z), a5);
        a6 = fmaf(nb, lof(vb.w), a6); a7 = fmaf(nb, hif(vb.w), a7);
        va = wa; vb = wb; na = ma; nb = mb;
        i0 = i1; i1 = i2;
    }

    const float k = 1.0f / 25.0f;
    float4 r0, r1;
    r0.x = (b0.x + lof(u1.x) + lof(u2.x) + lof(u3.x) + a0) * k;
    r0.y = (b0.y + hif(u1.x) + hif(u2.x) + hif(u3.x) + a1) * k;
    r0.z = (b0.z + lof(u1.y) + lof(u2.y) + lof(u3.y) + a2) * k;
    r0.w = (b0.w + hif(u1.y) + hif(u2.y) + hif(u3.y) + a3) * k;
    r1.x = (b1.x + lof(u1.z) + lof(u2.z) + lof(u3.z) + a4) * k;
    r1.y = (b1.y + hif(u1.z) + hif(u2.z) + hif(u3.z) + a5) * k;
    r1.z = (b1.z + lof(u1.w) + lof(u2.w) + lof(u3.w) + a6) * k;
    r1.w = (b1.w + hif(u1.w) + hif(u2.w) + hif(u3.w) + a7) * k;
    *(float4*)finP = r0;
    *(float4*)(finP + 4) = r1;
    *(float4*)cpyP = b0;
    *(float4*)(cpyP + 4) = b1;
}

// ---------------- host ----------------

extern "C" void kernel_launch(void* const* d_in, const int* in_sizes, int n_in,
                              void* d_out, int out_size, void* d_ws, size_t ws_size,
                              hipStream_t stream) {
    const int*   edge = (const int*)d_in[0];
    const float* embU = (const float*)d_in[1];
    const float* embI = (const float*)d_in[2];
    const int E = in_sizes[0] / 2;
    const int* row = edge;
    const int* col = edge + E;

    float* out  = (float*)d_out;
    float* finU = out;
    float* cu   = out + (size_t)U_CNT * DIM;
    float* finI = out + (size_t)2 * U_CNT * DIM;
    float* ci   = finI + (size_t)I_CNT * DIM;

    // workspace carve-up
    const size_t XB = (size_t)N_CNT * DIM * sizeof(bf16_t);   // 64 MB
    char* ws = (char*)d_ws;
    size_t p = 0;
    bf16_t* x0 = (bf16_t*)(ws + p); p += XB;
    bf16_t* y1 = (bf16_t*)(ws + p); p += XB;
    bf16_t* y2 = (bf16_t*)(ws + p); p += XB;
    bf16_t* y3 = (bf16_t*)(ws + p); p += XB;
    int*   cnt  = (int*)(ws + p);   p += ((size_t)N_CNT + 4) * sizeof(int);
    int*   off  = (int*)(ws + p);   p += ((size_t)N_CNT + 4) * sizeof(int);
    int*   cur  = (int*)(ws + p);   p += ((size_t)N_CNT + 4) * sizeof(int);
    float* dis  = (float*)(ws + p); p += ((size_t)N_CNT + 4) * sizeof(float);
    int*   bsum = (int*)(ws + p);   p += 1024 * sizeof(int);
    int2*  csr  = (int2*)(ws + p);  p += (size_t)E * sizeof(int2);              // 20 MB

    // adjusted item pointers (index by global node id)
    const float* embIadj = embI - (size_t)U_CNT * DIM;
    float* finIadj = finI - (size_t)U_CNT * DIM;
    float* ciadj   = ci   - (size_t)U_CNT * DIM;

    const int B = 256;
    const int nU4 = U_CNT * DIM / 4;
    const int nI4 = I_CNT * DIM / 4;
    const int gU4 = (nU4 + B - 1) / B;
    const int gI4 = (nI4 + B - 1) / B;
    const int gE  = (E + B - 1) / B;
    const int gN  = (N_CNT + B - 1) / B;
    const int gGather = N_CNT / 32;     // 15625, exact

    // 1. degree + normalization
    hipMemsetAsync(cnt, 0, (size_t)N_CNT * sizeof(int), stream);
    deg_cnt_kernel<<<gE, B, 0, stream>>>(col, cnt, E);
    dis_kernel<<<gN, B, 0, stream>>>(cnt, dis, N_CNT);

    // 2. CSR build
    scan1_kernel<<<NB1, 256, 0, stream>>>(cnt, bsum, N_CNT);
    scan2_kernel<<<1, 512, 0, stream>>>(bsum, NB1);
    scan3_kernel<<<NB1, 256, 0, stream>>>(cnt, bsum, off, cur, N_CNT, E);
    fill_kernel<<<gE, B, 0, stream>>>(row, col, dis, cur, csr, E);

    // 3. x0 -> bf16
    f2b_kernel<<<gU4, B, 0, stream>>>((const float4*)embU, (ushort4*)x0, nU4);
    f2b_kernel<<<gI4, B, 0, stream>>>((const float4*)embI,
                                      (ushort4*)(x0 + (size_t)U_CNT * DIM), nI4);

    // 4. layers 1..3 -> y1..y3; layer 4 fused with finalize + copies
    gather8_kernel<<<gGather, B, 0, stream>>>(off, csr, (const uint32_t*)x0, (uint4*)y1, E);
    gather8_kernel<<<gGather, B, 0, stream>>>(off, csr, (const uint32_t*)y1, (uint4*)y2, E);
    gather8_kernel<<<gGather, B, 0, stream>>>(off, csr, (const uint32_t*)y2, (uint4*)y3, E);
    gather_final_kernel<<<gGather, B, 0, stream>>>(off, csr, (const uint32_t*)y3,
        (const uint4*)y1, (const uint4*)y2,
        embU, embIadj, finU, finIadj, cu, ciadj, E);
}